// Round 9
// baseline (281.915 us; speedup 1.0000x reference)
//
#include <hip/hip_runtime.h>
#include <hip/hip_bf16.h>
#include <math.h>

namespace {

constexpr int MSTEPS = 60;
constexpr int NPTS   = 128;
constexpr int RPTS   = 32;
constexpr int BTOT   = 4096;   // RPTS * NPTS
constexpr int HID    = 128;
constexpr int PPB    = 8;      // paths per block (2 per wave x 4 waves)
constexpr int NBLK   = BTOT / PPB;  // 512 blocks -> 2 per CU
constexpr int STR    = 136;    // B row stride (bf16 elems), 272 B
constexpr int JSTRC  = 132;    // C row stride (f32), =4 mod 32

constexpr float F_T     = 1.5f;
constexpr float F_DT    = (float)(1.5 / 60.0);
constexpr float F_HALF  = (float)(0.5 * (1.5 / 60.0));
constexpr float F_SDT   = (float)0.15811388300841896659;  // sqrt(0.025)
constexpr float F_SHALF = (float)0.11180339887498948482;  // sqrt(0.0125)
constexpr float F_A     = (float)0.95393920141694565906;  // sqrt(1-0.3^2)
constexpr float F_IS2   = (float)0.70710678118654752440;
constexpr float F_R     = 0.02f;
constexpr float F_SIG   = 0.2f;
constexpr float F_SIGY  = 0.3f;
constexpr float F_RHO   = 0.3f;
constexpr float F_KY    = 1.2f;
constexpr float F_LBW   = 0.001f;
constexpr float F_LOGLBW = -6.90775527898213705205f;      // log(0.001)
constexpr float F_SA    = (float)(0.2 * 0.8);
constexpr float F_S2    = (float)(0.2 * 0.2);

typedef __attribute__((ext_vector_type(8))) short bf16x8;
typedef __attribute__((ext_vector_type(4))) float f32x4;
typedef __attribute__((ext_vector_type(2))) float f32x2;

// ---- packed 2xf32 VALU ops (VOP3P, CDNA2+; default op_sel: lo-lo, hi-hi) ----
__device__ __forceinline__ f32x2 pk_fma(f32x2 a, f32x2 b, f32x2 c) {
  f32x2 d;
  asm("v_pk_fma_f32 %0, %1, %2, %3" : "=v"(d) : "v"(a), "v"(b), "v"(c));
  return d;
}
__device__ __forceinline__ f32x2 pk_mul(f32x2 a, f32x2 b) {
  f32x2 d;
  asm("v_pk_mul_f32 %0, %1, %2" : "=v"(d) : "v"(a), "v"(b));
  return d;
}
__device__ __forceinline__ f32x2 sp2(float x) { return (f32x2){x, x}; }
__device__ __forceinline__ f32x2 mk2(float x, float y) { return (f32x2){x, y}; }

// RNE f32->bf16 (proven R3/R5/R7/R8)
__device__ __forceinline__ unsigned short f2bf(float x) {
  union { float f; unsigned u; } v; v.f = x;
  unsigned r = v.u + 0x7fffu + ((v.u >> 16) & 1u);
  return (unsigned short)(r >> 16);
}

// fast tanh: 1 - 2/(e^{2x}+1)
__device__ __forceinline__ float ftanh(float x) {
  float e = __expf(2.0f * x);
  return 1.0f - 2.0f / (e + 1.0f);
}

// x + dpp_perm(x); bound_ctrl=1 -> invalid lanes contribute 0  (proven R5/R7/R8)
template <int CTRL>
__device__ __forceinline__ float dpp_add(float x) {
  int y = __builtin_amdgcn_update_dpp(0, __float_as_int(x), CTRL, 0xf, 0xf, true);
  return x + __int_as_float(y);
}

// per-path (32-lane) all-sum: DPP row-of-16 tree + xor-16 shuffle (proven R7/R8).
__device__ __forceinline__ float path_allsum(float x) {
  x = dpp_add<0xB1>(x);   // quad_perm xor1
  x = dpp_add<0x4E>(x);   // quad_perm xor2
  x = dpp_add<0x124>(x);  // row_ror:4
  x = dpp_add<0x128>(x);  // row_ror:8  -> row-of-16 sums
  x += __shfl_xor(x, 16, 32);
  return x;
}

// ---- 2nd-order jet: v, d1=(d/dW0, d/dY0), d2=(d2/dW0^2, d2/dW0dY0) ----
struct Jet { float v; f32x2 d1; f32x2 d2; };

__device__ __forceinline__ Jet jmul(const Jet& a, const Jet& b) {
  Jet r;
  r.v  = a.v * b.v;
  r.d1 = pk_fma(sp2(a.v), b.d1, pk_mul(a.d1, sp2(b.v)));
  // t = (2*aw*bw, aw*by + ay*bw)
  f32x2 t = pk_fma(sp2(a.d1.x), b.d1, pk_mul(a.d1, sp2(b.d1.x)));
  r.d2 = pk_fma(sp2(a.v), b.d2, pk_fma(a.d2, sp2(b.v), t));
  return r;
}

__device__ __forceinline__ Jet jexp(const Jet& a) {
  float e = __expf(a.v);
  Jet r;
  r.v  = e;
  f32x2 e2 = sp2(e);
  r.d1 = pk_mul(e2, a.d1);
  r.d2 = pk_mul(e2, pk_fma(sp2(a.d1.x), a.d1, a.d2));  // e*(aw*aw+aww, aw*ay+awy)
  return r;
}

__device__ __forceinline__ Jet jtanh(const Jet& a) {
  float t  = ftanh(a.v);
  float f1 = 1.0f - t * t;
  float f2aw = -2.0f * t * f1 * a.d1.x;
  Jet r;
  r.v  = t;
  r.d1 = pk_mul(sp2(f1), a.d1);
  r.d2 = pk_fma(sp2(f1), a.d2, pk_mul(sp2(f2aw), a.d1));
  return r;
}

__device__ __forceinline__ Jet jstep(const Jet& base, const Jet& d, float cdt,
                                     const Jet& p, float cw) {
  Jet r;
  r.v  = base.v + d.v * cdt + p.v * cw;
  f32x2 cdt2 = sp2(cdt), cw2 = sp2(cw);
  r.d1 = pk_fma(d.d1, cdt2, pk_fma(p.d1, cw2, base.d1));
  r.d2 = pk_fma(d.d2, cdt2, pk_fma(p.d2, cw2, base.d2));
  return r;
}

__device__ __forceinline__ Jet ydec(const Jet& Y, float dt, float add) {
  const float c = -F_KY * dt;
  Jet r;
  r.v  = fmaf(c, Y.v, Y.v) + add;
  f32x2 c2 = sp2(c);
  r.d1 = pk_fma(c2, Y.d1, Y.d1);
  r.d2 = pk_fma(c2, Y.d2, Y.d2);
  return r;
}

__device__ __forceinline__ Jet driftvar(const Jet& pY, const Jet& pp) {
  Jet r;
  r.v  = F_R + F_SA * pY.v - 0.5f * F_S2 * pp.v;
  f32x2 sa2 = sp2(F_SA), ns2 = sp2(-0.5f * F_S2);
  r.d1 = pk_fma(sa2, pY.d1, pk_mul(ns2, pp.d1));
  r.d2 = pk_fma(sa2, pY.d2, pk_mul(ns2, pp.d2));
  return r;
}

} // namespace

// WAVE-AUTONOMOUS (R8 structure, unchanged): each wave owns 2 paths, full layer-2
// GEMM C[128][16] with W2 bf16 A-fragments in registers; B/C wave-private LDS;
// zero __syncthreads. This round: jet algebra on v_pk_*_f32 (packed 2xf32).
__global__ __launch_bounds__(256, 2) void ppgdpo_sim_kernel(
    const float* __restrict__ Wp, const float* __restrict__ Yp,
    const float* __restrict__ w1, const float* __restrict__ b1,
    const float* __restrict__ w2, const float* __restrict__ b2,
    const float* __restrict__ w3, const float* __restrict__ b3,
    const float* __restrict__ noise, float* __restrict__ ws) {
  __shared__ __align__(16) unsigned short Bsh[4][16 * STR];   // 17,408 B
  __shared__ __align__(16) float Csh[4][16 * JSTRC];          // 33,792 B

  const int t    = threadIdx.x;
  const int wv   = t >> 6;           // wave id (0..3)
  const int ln   = t & 63;           // lane in wave
  const int lp   = ln & 31;          // lane in path
  const int ph   = ln >> 5;          // path in wave (0/1)
  const int pblk = wv * 2 + ph;      // path in block
  const int b    = blockIdx.x * PPB + pblk;
  const int i    = b & (NPTS - 1);

  const int bx = ln & 15;            // MFMA col / A-row in tile
  const int kg = ln >> 4;            // MFMA k-group (0..3)

  // ---- W2 -> A fragments for ALL 8 row tiles (bf16, registers, once) ----
  bf16x8 A[8][4];
#pragma unroll
  for (int rt = 0; rt < 8; ++rt) {
#pragma unroll
    for (int kt = 0; kt < 4; ++kt) {
#pragma unroll
      for (int q = 0; q < 8; ++q)
        A[rt][kt][q] = (short)f2bf(w2[(kt * 32 + kg * 8 + q) * HID + rt * 16 + bx]);
    }
  }

  // per-lane layer-1/3 weights for owned units j0..j0+3 of this lane's path
  const int j0 = lp * 4;
  float w10[4], w11[4], w12[4], b1a[4], b2a[4], w3a[4];
  {
    float4 v;
    v = *(const float4*)(w1 + 0 * HID + j0); w10[0]=v.x; w10[1]=v.y; w10[2]=v.z; w10[3]=v.w;
    v = *(const float4*)(w1 + 1 * HID + j0); w11[0]=v.x; w11[1]=v.y; w11[2]=v.z; w11[3]=v.w;
    v = *(const float4*)(w1 + 2 * HID + j0); w12[0]=v.x; w12[1]=v.y; w12[2]=v.z; w12[3]=v.w;
    v = *(const float4*)(b1 + j0);           b1a[0]=v.x; b1a[1]=v.y; b1a[2]=v.z; b1a[3]=v.w;
    v = *(const float4*)(b2 + j0);           b2a[0]=v.x; b2a[1]=v.y; b2a[2]=v.z; b2a[3]=v.w;
    v = *(const float4*)(w3 + j0);           w3a[0]=v.x; w3a[1]=v.y; w3a[2]=v.z; w3a[3]=v.w;
  }
  const float b3r = b3[0];

  unsigned short* const myB = Bsh[wv];   // wave-private
  float* const myC = Csh[wv];            // wave-private
  const int cb = ph * 5;                 // this path's col base (0 or 5)

  auto mlp = [&](const Jet& Win, float tsub, const Jet& Yin) -> Jet {
    // ---- layer 1: 4 owned units -> RNE bf16 pack -> b64 write per comp ----
    Jet h[4];
#pragma unroll
    for (int u = 0; u < 4; ++u) {
      Jet a;
      a.v  = fmaf(w10[u], Win.v, fmaf(w11[u], tsub, fmaf(w12[u], Yin.v, b1a[u])));
      f32x2 wu0 = sp2(w10[u]), wu2 = sp2(w12[u]);
      a.d1 = pk_fma(wu0, Win.d1, pk_mul(wu2, Yin.d1));
      a.d2 = pk_fma(wu0, Win.d2, pk_mul(wu2, Yin.d2));
      h[u] = jtanh(a);
    }
    {
      float c0[4] = {h[0].v,    h[1].v,    h[2].v,    h[3].v};
      float c1[4] = {h[0].d1.x, h[1].d1.x, h[2].d1.x, h[3].d1.x};
      float c2[4] = {h[0].d1.y, h[1].d1.y, h[2].d1.y, h[3].d1.y};
      float c3[4] = {h[0].d2.x, h[1].d2.x, h[2].d2.x, h[3].d2.x};
      float c4[4] = {h[0].d2.y, h[1].d2.y, h[2].d2.y, h[3].d2.y};
      const float* cc[5] = {c0, c1, c2, c3, c4};
#pragma unroll
      for (int c = 0; c < 5; ++c) {
        unsigned u0 = __float_as_uint(cc[c][0]);
        unsigned u1 = __float_as_uint(cc[c][1]);
        unsigned u2 = __float_as_uint(cc[c][2]);
        unsigned u3 = __float_as_uint(cc[c][3]);
        uint2 wj;
        wj.x = ((u0 + 0x7fffu + ((u0 >> 16) & 1u)) >> 16)
             | ((u1 + 0x7fffu + ((u1 >> 16) & 1u)) & 0xffff0000u);
        wj.y = ((u2 + 0x7fffu + ((u2 >> 16) & 1u)) >> 16)
             | ((u3 + 0x7fffu + ((u3 >> 16) & 1u)) & 0xffff0000u);
        *reinterpret_cast<uint2*>(&myB[(cb + c) * STR + j0]) = wj;
      }
    }
    // (no barrier: same-wave DS ops are in-order)
    // ---- MFMA: 8 row tiles x 4 k tiles, single bf16 W2 ----
    bf16x8 bb[4];
#pragma unroll
    for (int kt = 0; kt < 4; ++kt)
      bb[kt] = *reinterpret_cast<const bf16x8*>(&myB[bx * STR + kt * 32 + kg * 8]);
#pragma unroll
    for (int rt = 0; rt < 8; ++rt) {
      f32x4 a_ = {0.f, 0.f, 0.f, 0.f};
#pragma unroll
      for (int kt = 0; kt < 4; ++kt)
        a_ = __builtin_amdgcn_mfma_f32_16x16x32_bf16(A[rt][kt], bb[kt], a_, 0, 0, 0);
      *reinterpret_cast<f32x4*>(&myC[bx * JSTRC + rt * 16 + kg * 4]) = a_;
    }
    // (no barrier)
    // ---- gather a2 (f32) + tanh + layer 3 + per-path reduction ----
    f32x4 av[5];
#pragma unroll
    for (int c = 0; c < 5; ++c)
      av[c] = *reinterpret_cast<const f32x4*>(&myC[(cb + c) * JSTRC + j0]);
    float s0 = 0.f;
    f32x2 sd1 = sp2(0.f), sd2 = sp2(0.f);
#pragma unroll
    for (int u = 0; u < 4; ++u) {
      Jet a2;
      a2.v  = av[0][u] + b2a[u];
      a2.d1 = mk2(av[1][u], av[2][u]);
      a2.d2 = mk2(av[3][u], av[4][u]);
      Jet hh = jtanh(a2);
      f32x2 w32 = sp2(w3a[u]);
      s0  = fmaf(hh.v, w3a[u], s0);
      sd1 = pk_fma(hh.d1, w32, sd1);
      sd2 = pk_fma(hh.d2, w32, sd2);
    }
    Jet pi;
    pi.v = path_allsum(s0) + b3r;
    pi.d1 = mk2(path_allsum(sd1.x), path_allsum(sd1.y));
    pi.d2 = mk2(path_allsum(sd2.x), path_allsum(sd2.y));
    return pi;
  };

  // ---- initial state jets (lanes of a path in lockstep) ----
  const float W0 = Wp[i];
  Jet L;
  L.v  = __logf(fmaxf(W0, F_LBW));
  L.d1 = mk2(1.0f / W0, 0.0f);
  L.d2 = mk2(-1.0f / (W0 * W0), 0.0f);
  Jet Yj;
  Yj.v  = Yp[i];
  Yj.d1 = mk2(0.0f, 1.0f);
  Yj.d2 = sp2(0.0f);
  float tmt = F_T;

  for (int m = 0; m < MSTEPS; ++m) {
    const float* nz = noise + (size_t)(m * 4) * BTOT + b;
    float z1b = nz[0];
    float z2b = nz[BTOT];
    float z1n = nz[2 * BTOT];
    float z2n = nz[3 * BTOT];
    float zWb = z1b, zYb = F_RHO * z1b + F_A * z2b;
    float zWn = z1n, zYn = F_RHO * z1n + F_A * z2n;
    float zWh1 = (zWb + zWn) * F_IS2, zYh1 = (zYb + zYn) * F_IS2;
    float zWh2 = (zWb - zWn) * F_IS2, zYh2 = (zYb - zYn) * F_IS2;

    Jet Win  = jexp(L);
    Jet pi_t = mlp(Win, tmt, Yj);

    Jet pY = jmul(pi_t, Yj);
    Jet pp = jmul(pi_t, pi_t);
    Jet dv = driftvar(pY, pp);

    float cWc  = F_SIG * (F_SDT * zWb);
    Jet lWc = jstep(L, dv, F_DT, pi_t, cWc);                      // coarse
    Jet Yc  = ydec(Yj, F_DT, F_SIGY * (F_SDT * zYb));

    float cWh1 = F_SIG * (F_SHALF * zWh1);
    Jet lWh = jstep(L, dv, F_HALF, pi_t, cWh1);                   // half 1
    Jet Yh  = ydec(Yj, F_HALF, F_SIGY * (F_SHALF * zYh1));

    Jet pih = mlp(jexp(lWh), tmt - F_HALF, Yh);                   // half 2
    Jet pYh = jmul(pih, Yh);
    Jet pph = jmul(pih, pih);
    Jet dvh = driftvar(pYh, pph);
    float cWh2 = F_SIG * (F_SHALF * zWh2);
    Jet lWf = jstep(lWh, dvh, F_HALF, pih, cWh2);
    Jet Yf  = ydec(Yh, F_HALF, F_SIGY * (F_SHALF * zYh2));

    // Richardson combination (scalar fma: 2*f - c is 1 inst/comp already)
    Jet raw, Yn;
    raw.v  = 2.0f * lWf.v - lWc.v;
    raw.d1 = mk2(2.0f * lWf.d1.x - lWc.d1.x, 2.0f * lWf.d1.y - lWc.d1.y);
    raw.d2 = mk2(2.0f * lWf.d2.x - lWc.d2.x, 2.0f * lWf.d2.y - lWc.d2.y);
    Yn.v   = 2.0f * Yf.v - Yc.v;
    Yn.d1  = mk2(2.0f * Yf.d1.x - Yc.d1.x, 2.0f * Yf.d1.y - Yc.d1.y);
    Yn.d2  = mk2(2.0f * Yf.d2.x - Yc.d2.x, 2.0f * Yf.d2.y - Yc.d2.y);

    // wealth floor: below log(LB_W) clamp value, zero derivatives
    bool ok = raw.v > F_LOGLBW;
    L.v  = ok ? raw.v  : F_LOGLBW;
    L.d1 = ok ? raw.d1 : sp2(0.0f);
    L.d2 = ok ? raw.d2 : sp2(0.0f);
    Yj = Yn;
    tmt -= F_DT;
  }

  // U = -0.25*exp(-4L); per-path dU/dW0, d2U/dW0^2, d2U/dW0dY0
  if (lp == 0) {
    float g = __expf(-4.0f * L.v);
    ws[b]            = g * L.d1.x;
    ws[BTOT + b]     = g * (L.d2.x - 4.0f * L.d1.x * L.d1.x);
    ws[2 * BTOT + b] = g * (L.d2.y - 4.0f * L.d1.x * L.d1.y);
  }
}

__global__ void ppgdpo_reduce_kernel(const float* __restrict__ ws,
                                     const float* __restrict__ Wp,
                                     const float* __restrict__ Yp,
                                     float* __restrict__ out) {
  int i = threadIdx.x;  // 128 threads
  float sU = 0.f, sWW = 0.f, sWY = 0.f;
  for (int r = 0; r < RPTS; ++r) {
    int b = r * NPTS + i;
    sU  += ws[b];
    sWW += ws[BTOT + b];
    sWY += ws[2 * BTOT + b];
  }
  float lam = sU  * (1.0f / 32768.0f);
  float dW  = sWW * (1.0f / 1048576.0f);
  float dY  = sWY * (1.0f / 1048576.0f);

  float mu    = F_SIG * (0.8f * Yp[i]);
  float coeff = -1.0f / (Wp[i] * dW + 1e-8f);
  float myo   = coeff * (lam * (mu / F_S2));
  float hedge = coeff * ((float)(0.2 * 0.3 * 0.3) * dY / F_S2);
  float pi = myo + hedge;
  pi = fminf(fmaxf(pi, -2.0f), 2.0f);
  out[i] = pi;
}

extern "C" void kernel_launch(void* const* d_in, const int* in_sizes, int n_in,
                              void* d_out, int out_size, void* d_ws, size_t ws_size,
                              hipStream_t stream) {
  const float* W     = (const float*)d_in[0];
  const float* Y     = (const float*)d_in[2];
  const float* w1    = (const float*)d_in[3];
  const float* b1    = (const float*)d_in[4];
  const float* w2    = (const float*)d_in[5];
  const float* b2    = (const float*)d_in[6];
  const float* w3    = (const float*)d_in[7];
  const float* b3    = (const float*)d_in[8];
  const float* noise = (const float*)d_in[9];
  float* ws = (float*)d_ws;
  float* out = (float*)d_out;

  ppgdpo_sim_kernel<<<dim3(NBLK), dim3(256), 0, stream>>>(
      W, Y, w1, b1, w2, b2, w3, b3, noise, ws);
  ppgdpo_reduce_kernel<<<dim3(1), dim3(128), 0, stream>>>(ws, W, Y, out);
}

// Round 10
// 245.466 us; speedup vs baseline: 1.1485x; 1.1485x over previous
//
#include <hip/hip_runtime.h>
#include <hip/hip_bf16.h>
#include <math.h>

namespace {

constexpr int MSTEPS = 60;
constexpr int NPTS   = 128;
constexpr int RPTS   = 32;
constexpr int BTOT   = 4096;   // RPTS * NPTS
constexpr int HID    = 128;
constexpr int PPB    = 8;      // paths per block (2 per wave x 4 waves)
constexpr int NBLK   = BTOT / PPB;  // 512 blocks -> 2 per CU
constexpr int STR    = 136;    // B row stride (bf16 elems), 272 B
constexpr int JSTRC  = 132;    // C row stride (f32), =4 mod 32

constexpr float F_T     = 1.5f;
constexpr float F_DT    = (float)(1.5 / 60.0);
constexpr float F_HALF  = (float)(0.5 * (1.5 / 60.0));
constexpr float F_SDT   = (float)0.15811388300841896659;  // sqrt(0.025)
constexpr float F_SHALF = (float)0.11180339887498948482;  // sqrt(0.0125)
constexpr float F_A     = (float)0.95393920141694565906;  // sqrt(1-0.3^2)
constexpr float F_IS2   = (float)0.70710678118654752440;
constexpr float F_R     = 0.02f;
constexpr float F_SIG   = 0.2f;
constexpr float F_SIGY  = 0.3f;
constexpr float F_RHO   = 0.3f;
constexpr float F_KY    = 1.2f;
constexpr float F_LBW   = 0.001f;
constexpr float F_LOGLBW = -6.90775527898213705205f;      // log(0.001)
constexpr float F_SA    = (float)(0.2 * 0.8);
constexpr float F_S2    = (float)(0.2 * 0.2);

typedef __attribute__((ext_vector_type(8))) short bf16x8;
typedef __attribute__((ext_vector_type(4))) float f32x4;

// RNE f32->bf16 (proven R3/R5/R7/R8)
__device__ __forceinline__ unsigned short f2bf(float x) {
  union { float f; unsigned u; } v; v.f = x;
  unsigned r = v.u + 0x7fffu + ((v.u >> 16) & 1u);
  return (unsigned short)(r >> 16);
}

// fast tanh: 1 - 2*rcp(e^{2x}+1).
// THE R10 CHANGE: without fast-math, "2/(e+1)" lowered to the full IEEE divide
// sequence (~11 VALU inst); v_rcp_f32 is 1 inst at ~1 ulp. 16 jtanh/step made
// divisions ~25% of the VALU budget. rcp(+inf)=0 -> exact tanh saturation.
__device__ __forceinline__ float ftanh(float x) {
  float e = __expf(2.0f * x);
  return 1.0f - 2.0f * __builtin_amdgcn_rcpf(e + 1.0f);
}

// x + dpp_perm(x); bound_ctrl=1 -> invalid lanes contribute 0  (proven R5/R7/R8)
template <int CTRL>
__device__ __forceinline__ float dpp_add(float x) {
  int y = __builtin_amdgcn_update_dpp(0, __float_as_int(x), CTRL, 0xf, 0xf, true);
  return x + __int_as_float(y);
}

// per-path (32-lane) all-sum: DPP row-of-16 tree + xor-16 shuffle (proven R7/R8).
__device__ __forceinline__ float path_allsum(float x) {
  x = dpp_add<0xB1>(x);   // quad_perm xor1
  x = dpp_add<0x4E>(x);   // quad_perm xor2
  x = dpp_add<0x124>(x);  // row_ror:4
  x = dpp_add<0x128>(x);  // row_ror:8  -> row-of-16 sums
  x += __shfl_xor(x, 16, 32);
  return x;
}

// ---- 2nd-order jet: value, d/dW0, d/dY0, d2/dW0^2, d2/dW0dY0 ----
struct Jet { float v, w, y, ww, wy; };

__device__ __forceinline__ Jet jmul(const Jet& a, const Jet& b) {
  Jet r;
  r.v  = a.v * b.v;
  r.w  = a.v * b.w + a.w * b.v;
  r.y  = a.v * b.y + a.y * b.v;
  r.ww = a.v * b.ww + 2.0f * a.w * b.w + a.ww * b.v;
  r.wy = a.v * b.wy + a.w * b.y + a.y * b.w + a.wy * b.v;
  return r;
}

__device__ __forceinline__ Jet jexp(const Jet& a) {
  float e = __expf(a.v);
  Jet r;
  r.v  = e;
  r.w  = e * a.w;
  r.y  = e * a.y;
  r.ww = e * (a.ww + a.w * a.w);
  r.wy = e * (a.wy + a.w * a.y);
  return r;
}

__device__ __forceinline__ Jet jtanh(const Jet& a) {
  float t  = ftanh(a.v);
  float f1 = 1.0f - t * t;
  float f2 = -2.0f * t * f1;
  Jet r;
  r.v  = t;
  r.w  = f1 * a.w;
  r.y  = f1 * a.y;
  r.ww = f1 * a.ww + f2 * a.w * a.w;
  r.wy = f1 * a.wy + f2 * a.w * a.y;
  return r;
}

__device__ __forceinline__ Jet jstep(const Jet& base, const Jet& d, float cdt,
                                     const Jet& p, float cw) {
  Jet r;
  r.v  = base.v  + d.v  * cdt + p.v  * cw;
  r.w  = base.w  + d.w  * cdt + p.w  * cw;
  r.y  = base.y  + d.y  * cdt + p.y  * cw;
  r.ww = base.ww + d.ww * cdt + p.ww * cw;
  r.wy = base.wy + d.wy * cdt + p.wy * cw;
  return r;
}

__device__ __forceinline__ Jet ydec(const Jet& Y, float dt, float add) {
  Jet r;
  r.v  = Y.v  - F_KY * Y.v  * dt + add;
  r.w  = Y.w  - F_KY * Y.w  * dt;
  r.y  = Y.y  - F_KY * Y.y  * dt;
  r.ww = Y.ww - F_KY * Y.ww * dt;
  r.wy = Y.wy - F_KY * Y.wy * dt;
  return r;
}

__device__ __forceinline__ Jet driftvar(const Jet& pY, const Jet& pp) {
  Jet r;
  r.v  = F_R + F_SA * pY.v  - 0.5f * F_S2 * pp.v;
  r.w  =       F_SA * pY.w  - 0.5f * F_S2 * pp.w;
  r.y  =       F_SA * pY.y  - 0.5f * F_S2 * pp.y;
  r.ww =       F_SA * pY.ww - 0.5f * F_S2 * pp.ww;
  r.wy =       F_SA * pY.wy - 0.5f * F_S2 * pp.wy;
  return r;
}

} // namespace

// WAVE-AUTONOMOUS (R8 structure, unchanged): each wave owns 2 paths, full layer-2
// GEMM C[128][16] with W2 bf16 A-fragments in registers; B/C wave-private LDS;
// zero __syncthreads.
__global__ __launch_bounds__(256, 2) void ppgdpo_sim_kernel(
    const float* __restrict__ Wp, const float* __restrict__ Yp,
    const float* __restrict__ w1, const float* __restrict__ b1,
    const float* __restrict__ w2, const float* __restrict__ b2,
    const float* __restrict__ w3, const float* __restrict__ b3,
    const float* __restrict__ noise, float* __restrict__ ws) {
  __shared__ __align__(16) unsigned short Bsh[4][16 * STR];   // 17,408 B
  __shared__ __align__(16) float Csh[4][16 * JSTRC];          // 33,792 B

  const int t    = threadIdx.x;
  const int wv   = t >> 6;           // wave id (0..3)
  const int ln   = t & 63;           // lane in wave
  const int lp   = ln & 31;          // lane in path
  const int ph   = ln >> 5;          // path in wave (0/1)
  const int pblk = wv * 2 + ph;      // path in block
  const int b    = blockIdx.x * PPB + pblk;
  const int i    = b & (NPTS - 1);

  const int bx = ln & 15;            // MFMA col / A-row in tile
  const int kg = ln >> 4;            // MFMA k-group (0..3)

  // ---- W2 -> A fragments for ALL 8 row tiles (bf16, registers, once) ----
  bf16x8 A[8][4];
#pragma unroll
  for (int rt = 0; rt < 8; ++rt) {
#pragma unroll
    for (int kt = 0; kt < 4; ++kt) {
#pragma unroll
      for (int q = 0; q < 8; ++q)
        A[rt][kt][q] = (short)f2bf(w2[(kt * 32 + kg * 8 + q) * HID + rt * 16 + bx]);
    }
  }

  // per-lane layer-1/3 weights for owned units j0..j0+3 of this lane's path
  const int j0 = lp * 4;
  float w10[4], w11[4], w12[4], b1a[4], b2a[4], w3a[4];
  {
    float4 v;
    v = *(const float4*)(w1 + 0 * HID + j0); w10[0]=v.x; w10[1]=v.y; w10[2]=v.z; w10[3]=v.w;
    v = *(const float4*)(w1 + 1 * HID + j0); w11[0]=v.x; w11[1]=v.y; w11[2]=v.z; w11[3]=v.w;
    v = *(const float4*)(w1 + 2 * HID + j0); w12[0]=v.x; w12[1]=v.y; w12[2]=v.z; w12[3]=v.w;
    v = *(const float4*)(b1 + j0);           b1a[0]=v.x; b1a[1]=v.y; b1a[2]=v.z; b1a[3]=v.w;
    v = *(const float4*)(b2 + j0);           b2a[0]=v.x; b2a[1]=v.y; b2a[2]=v.z; b2a[3]=v.w;
    v = *(const float4*)(w3 + j0);           w3a[0]=v.x; w3a[1]=v.y; w3a[2]=v.z; w3a[3]=v.w;
  }
  const float b3r = b3[0];

  unsigned short* const myB = Bsh[wv];   // wave-private
  float* const myC = Csh[wv];            // wave-private
  const int cb = ph * 5;                 // this path's col base (0 or 5)

  auto mlp = [&](const Jet& Win, float tsub, const Jet& Yin) -> Jet {
    // ---- layer 1: 4 owned units -> RNE bf16 pack -> b64 write per comp ----
    Jet h[4];
#pragma unroll
    for (int u = 0; u < 4; ++u) {
      Jet a;
      a.v  = fmaf(w10[u], Win.v, fmaf(w11[u], tsub, fmaf(w12[u], Yin.v, b1a[u])));
      a.w  = fmaf(w10[u], Win.w,  w12[u] * Yin.w);
      a.y  = fmaf(w10[u], Win.y,  w12[u] * Yin.y);
      a.ww = fmaf(w10[u], Win.ww, w12[u] * Yin.ww);
      a.wy = fmaf(w10[u], Win.wy, w12[u] * Yin.wy);
      h[u] = jtanh(a);
    }
    {
      float c0[4] = {h[0].v,  h[1].v,  h[2].v,  h[3].v};
      float c1[4] = {h[0].w,  h[1].w,  h[2].w,  h[3].w};
      float c2[4] = {h[0].y,  h[1].y,  h[2].y,  h[3].y};
      float c3[4] = {h[0].ww, h[1].ww, h[2].ww, h[3].ww};
      float c4[4] = {h[0].wy, h[1].wy, h[2].wy, h[3].wy};
      const float* cc[5] = {c0, c1, c2, c3, c4};
#pragma unroll
      for (int c = 0; c < 5; ++c) {
        unsigned u0 = __float_as_uint(cc[c][0]);
        unsigned u1 = __float_as_uint(cc[c][1]);
        unsigned u2 = __float_as_uint(cc[c][2]);
        unsigned u3 = __float_as_uint(cc[c][3]);
        uint2 wj;
        wj.x = ((u0 + 0x7fffu + ((u0 >> 16) & 1u)) >> 16)
             | ((u1 + 0x7fffu + ((u1 >> 16) & 1u)) & 0xffff0000u);
        wj.y = ((u2 + 0x7fffu + ((u2 >> 16) & 1u)) >> 16)
             | ((u3 + 0x7fffu + ((u3 >> 16) & 1u)) & 0xffff0000u);
        *reinterpret_cast<uint2*>(&myB[(cb + c) * STR + j0]) = wj;
      }
    }
    // (no barrier: same-wave DS ops are in-order)
    // ---- MFMA: 8 row tiles x 4 k tiles, single bf16 W2 ----
    bf16x8 bb[4];
#pragma unroll
    for (int kt = 0; kt < 4; ++kt)
      bb[kt] = *reinterpret_cast<const bf16x8*>(&myB[bx * STR + kt * 32 + kg * 8]);
#pragma unroll
    for (int rt = 0; rt < 8; ++rt) {
      f32x4 a_ = {0.f, 0.f, 0.f, 0.f};
#pragma unroll
      for (int kt = 0; kt < 4; ++kt)
        a_ = __builtin_amdgcn_mfma_f32_16x16x32_bf16(A[rt][kt], bb[kt], a_, 0, 0, 0);
      *reinterpret_cast<f32x4*>(&myC[bx * JSTRC + rt * 16 + kg * 4]) = a_;
    }
    // (no barrier)
    // ---- gather a2 (f32 float4) + tanh + layer 3 + per-path reduction ----
    float4 av[5];
#pragma unroll
    for (int c = 0; c < 5; ++c)
      av[c] = *reinterpret_cast<const float4*>(&myC[(cb + c) * JSTRC + j0]);
    float s[5] = {0.f, 0.f, 0.f, 0.f, 0.f};
#pragma unroll
    for (int u = 0; u < 4; ++u) {
      Jet a2;
      a2.v  = (u == 0 ? av[0].x : u == 1 ? av[0].y : u == 2 ? av[0].z : av[0].w) + b2a[u];
      a2.w  = (u == 0 ? av[1].x : u == 1 ? av[1].y : u == 2 ? av[1].z : av[1].w);
      a2.y  = (u == 0 ? av[2].x : u == 1 ? av[2].y : u == 2 ? av[2].z : av[2].w);
      a2.ww = (u == 0 ? av[3].x : u == 1 ? av[3].y : u == 2 ? av[3].z : av[3].w);
      a2.wy = (u == 0 ? av[4].x : u == 1 ? av[4].y : u == 2 ? av[4].z : av[4].w);
      Jet hh = jtanh(a2);
      s[0] = fmaf(hh.v,  w3a[u], s[0]);
      s[1] = fmaf(hh.w,  w3a[u], s[1]);
      s[2] = fmaf(hh.y,  w3a[u], s[2]);
      s[3] = fmaf(hh.ww, w3a[u], s[3]);
      s[4] = fmaf(hh.wy, w3a[u], s[4]);
    }
#pragma unroll
    for (int c = 0; c < 5; ++c) s[c] = path_allsum(s[c]);
    Jet pi;
    pi.v = s[0] + b3r; pi.w = s[1]; pi.y = s[2]; pi.ww = s[3]; pi.wy = s[4];
    return pi;
  };

  // ---- initial state jets (lanes of a path in lockstep) ----
  const float W0 = Wp[i];
  Jet L;
  L.v = __logf(fmaxf(W0, F_LBW));
  L.w = 1.0f / W0;
  L.y = 0.0f;
  L.ww = -1.0f / (W0 * W0);
  L.wy = 0.0f;
  Jet Yj;
  Yj.v = Yp[i]; Yj.w = 0.0f; Yj.y = 1.0f; Yj.ww = 0.0f; Yj.wy = 0.0f;
  float tmt = F_T;

  for (int m = 0; m < MSTEPS; ++m) {
    const float* nz = noise + (size_t)(m * 4) * BTOT + b;
    float z1b = nz[0];
    float z2b = nz[BTOT];
    float z1n = nz[2 * BTOT];
    float z2n = nz[3 * BTOT];
    float zWb = z1b, zYb = F_RHO * z1b + F_A * z2b;
    float zWn = z1n, zYn = F_RHO * z1n + F_A * z2n;
    float zWh1 = (zWb + zWn) * F_IS2, zYh1 = (zYb + zYn) * F_IS2;
    float zWh2 = (zWb - zWn) * F_IS2, zYh2 = (zYb - zYn) * F_IS2;

    Jet Win  = jexp(L);
    Jet pi_t = mlp(Win, tmt, Yj);

    Jet pY = jmul(pi_t, Yj);
    Jet pp = jmul(pi_t, pi_t);
    Jet dv = driftvar(pY, pp);

    float cWc  = F_SIG * (F_SDT * zWb);
    Jet lWc = jstep(L, dv, F_DT, pi_t, cWc);                      // coarse
    Jet Yc  = ydec(Yj, F_DT, F_SIGY * (F_SDT * zYb));

    float cWh1 = F_SIG * (F_SHALF * zWh1);
    Jet lWh = jstep(L, dv, F_HALF, pi_t, cWh1);                   // half 1
    Jet Yh  = ydec(Yj, F_HALF, F_SIGY * (F_SHALF * zYh1));

    Jet pih = mlp(jexp(lWh), tmt - F_HALF, Yh);                   // half 2
    Jet pYh = jmul(pih, Yh);
    Jet pph = jmul(pih, pih);
    Jet dvh = driftvar(pYh, pph);
    float cWh2 = F_SIG * (F_SHALF * zWh2);
    Jet lWf = jstep(lWh, dvh, F_HALF, pih, cWh2);
    Jet Yf  = ydec(Yh, F_HALF, F_SIGY * (F_SHALF * zYh2));

    // Richardson combination
    Jet raw, Yn;
    raw.v  = 2.0f * lWf.v  - lWc.v;
    raw.w  = 2.0f * lWf.w  - lWc.w;
    raw.y  = 2.0f * lWf.y  - lWc.y;
    raw.ww = 2.0f * lWf.ww - lWc.ww;
    raw.wy = 2.0f * lWf.wy - lWc.wy;
    Yn.v  = 2.0f * Yf.v  - Yc.v;
    Yn.w  = 2.0f * Yf.w  - Yc.w;
    Yn.y  = 2.0f * Yf.y  - Yc.y;
    Yn.ww = 2.0f * Yf.ww - Yc.ww;
    Yn.wy = 2.0f * Yf.wy - Yc.wy;

    // wealth floor: below log(LB_W) clamp value, zero derivatives
    bool ok = raw.v > F_LOGLBW;
    L.v  = ok ? raw.v  : F_LOGLBW;
    L.w  = ok ? raw.w  : 0.0f;
    L.y  = ok ? raw.y  : 0.0f;
    L.ww = ok ? raw.ww : 0.0f;
    L.wy = ok ? raw.wy : 0.0f;
    Yj = Yn;
    tmt -= F_DT;
  }

  // U = -0.25*exp(-4L); per-path dU/dW0, d2U/dW0^2, d2U/dW0dY0
  if (lp == 0) {
    float g = __expf(-4.0f * L.v);
    ws[b]            = g * L.w;
    ws[BTOT + b]     = g * (L.ww - 4.0f * L.w * L.w);
    ws[2 * BTOT + b] = g * (L.wy - 4.0f * L.w * L.y);
  }
}

__global__ void ppgdpo_reduce_kernel(const float* __restrict__ ws,
                                     const float* __restrict__ Wp,
                                     const float* __restrict__ Yp,
                                     float* __restrict__ out) {
  int i = threadIdx.x;  // 128 threads
  float sU = 0.f, sWW = 0.f, sWY = 0.f;
  for (int r = 0; r < RPTS; ++r) {
    int b = r * NPTS + i;
    sU  += ws[b];
    sWW += ws[BTOT + b];
    sWY += ws[2 * BTOT + b];
  }
  float lam = sU  * (1.0f / 32768.0f);
  float dW  = sWW * (1.0f / 1048576.0f);
  float dY  = sWY * (1.0f / 1048576.0f);

  float mu    = F_SIG * (0.8f * Yp[i]);
  float coeff = -1.0f / (Wp[i] * dW + 1e-8f);
  float myo   = coeff * (lam * (mu / F_S2));
  float hedge = coeff * ((float)(0.2 * 0.3 * 0.3) * dY / F_S2);
  float pi = myo + hedge;
  pi = fminf(fmaxf(pi, -2.0f), 2.0f);
  out[i] = pi;
}

extern "C" void kernel_launch(void* const* d_in, const int* in_sizes, int n_in,
                              void* d_out, int out_size, void* d_ws, size_t ws_size,
                              hipStream_t stream) {
  const float* W     = (const float*)d_in[0];
  const float* Y     = (const float*)d_in[2];
  const float* w1    = (const float*)d_in[3];
  const float* b1    = (const float*)d_in[4];
  const float* w2    = (const float*)d_in[5];
  const float* b2    = (const float*)d_in[6];
  const float* w3    = (const float*)d_in[7];
  const float* b3    = (const float*)d_in[8];
  const float* noise = (const float*)d_in[9];
  float* ws = (float*)d_ws;
  float* out = (float*)d_out;

  ppgdpo_sim_kernel<<<dim3(NBLK), dim3(256), 0, stream>>>(
      W, Y, w1, b1, w2, b2, w3, b3, noise, ws);
  ppgdpo_reduce_kernel<<<dim3(1), dim3(128), 0, stream>>>(ws, W, Y, out);
}

// Round 11
// 231.291 us; speedup vs baseline: 1.2189x; 1.0613x over previous
//
#include <hip/hip_runtime.h>
#include <hip/hip_bf16.h>
#include <math.h>

namespace {

constexpr int MSTEPS = 60;
constexpr int NPTS   = 128;
constexpr int RPTS   = 32;
constexpr int BTOT   = 4096;   // RPTS * NPTS
constexpr int HID    = 128;
constexpr int PPB    = 8;      // paths per block (2 per wave x 4 waves)
constexpr int NBLK   = BTOT / PPB;  // 512 blocks -> 2 per CU
constexpr int STR    = 136;    // B row stride (bf16 elems), 272 B
constexpr int JSTRC  = 132;    // C row stride (f32), =4 mod 32

constexpr float F_T     = 1.5f;
constexpr float F_DT    = (float)(1.5 / 60.0);
constexpr float F_HALF  = (float)(0.5 * (1.5 / 60.0));
constexpr float F_SDT   = (float)0.15811388300841896659;  // sqrt(0.025)
constexpr float F_SHALF = (float)0.11180339887498948482;  // sqrt(0.0125)
constexpr float F_A     = (float)0.95393920141694565906;  // sqrt(1-0.3^2)
constexpr float F_IS2   = (float)0.70710678118654752440;
constexpr float F_R     = 0.02f;
constexpr float F_SIG   = 0.2f;
constexpr float F_SIGY  = 0.3f;
constexpr float F_RHO   = 0.3f;
constexpr float F_KY    = 1.2f;
constexpr float F_LBW   = 0.001f;
constexpr float F_LOGLBW = -6.90775527898213705205f;      // log(0.001)
constexpr float F_SA    = (float)(0.2 * 0.8);
constexpr float F_S2    = (float)(0.2 * 0.2);

typedef __attribute__((ext_vector_type(8))) short bf16x8;
typedef __attribute__((ext_vector_type(4))) float f32x4;

// RNE f32->bf16 (scalar; used for the one-time W2 A-fragment split)
__device__ __forceinline__ unsigned short f2bf(float x) {
  union { float f; unsigned u; } v; v.f = x;
  unsigned r = v.u + 0x7fffu + ((v.u >> 16) & 1u);
  return (unsigned short)(r >> 16);
}

// THE R11 CHANGE (isolated retest of R6's prime-innocent element):
// HW packed f32->2xbf16, dst.lo = bf16(src0), dst.hi = bf16(src1) per the
// guide's T12 recipe. Replaces ~5-6 VALU inst/value of manual RNE with 1 inst
// per 2 values in the per-eval B-pack (~10% of the VALU budget).
__device__ __forceinline__ unsigned pack2(float lo, float hi) {
  unsigned r;
  asm("v_cvt_pk_bf16_f32 %0, %1, %2" : "=v"(r) : "v"(lo), "v"(hi));
  return r;
}

// fast tanh: 1 - 2*rcp(e^{2x}+1)  (R10-proven; rcp(+inf)=0 -> exact saturation)
__device__ __forceinline__ float ftanh(float x) {
  float e = __expf(2.0f * x);
  return 1.0f - 2.0f * __builtin_amdgcn_rcpf(e + 1.0f);
}

// x + dpp_perm(x); bound_ctrl=1 -> invalid lanes contribute 0  (proven R5/R7/R8)
template <int CTRL>
__device__ __forceinline__ float dpp_add(float x) {
  int y = __builtin_amdgcn_update_dpp(0, __float_as_int(x), CTRL, 0xf, 0xf, true);
  return x + __int_as_float(y);
}

// per-path (32-lane) all-sum: DPP row-of-16 tree + xor-16 shuffle (proven R7/R8).
__device__ __forceinline__ float path_allsum(float x) {
  x = dpp_add<0xB1>(x);   // quad_perm xor1
  x = dpp_add<0x4E>(x);   // quad_perm xor2
  x = dpp_add<0x124>(x);  // row_ror:4
  x = dpp_add<0x128>(x);  // row_ror:8  -> row-of-16 sums
  x += __shfl_xor(x, 16, 32);
  return x;
}

// ---- 2nd-order jet: value, d/dW0, d/dY0, d2/dW0^2, d2/dW0dY0 ----
struct Jet { float v, w, y, ww, wy; };

__device__ __forceinline__ Jet jmul(const Jet& a, const Jet& b) {
  Jet r;
  r.v  = a.v * b.v;
  r.w  = a.v * b.w + a.w * b.v;
  r.y  = a.v * b.y + a.y * b.v;
  r.ww = a.v * b.ww + 2.0f * a.w * b.w + a.ww * b.v;
  r.wy = a.v * b.wy + a.w * b.y + a.y * b.w + a.wy * b.v;
  return r;
}

__device__ __forceinline__ Jet jexp(const Jet& a) {
  float e = __expf(a.v);
  Jet r;
  r.v  = e;
  r.w  = e * a.w;
  r.y  = e * a.y;
  r.ww = e * (a.ww + a.w * a.w);
  r.wy = e * (a.wy + a.w * a.y);
  return r;
}

__device__ __forceinline__ Jet jtanh(const Jet& a) {
  float t  = ftanh(a.v);
  float f1 = 1.0f - t * t;
  float f2 = -2.0f * t * f1;
  Jet r;
  r.v  = t;
  r.w  = f1 * a.w;
  r.y  = f1 * a.y;
  r.ww = f1 * a.ww + f2 * a.w * a.w;
  r.wy = f1 * a.wy + f2 * a.w * a.y;
  return r;
}

__device__ __forceinline__ Jet jstep(const Jet& base, const Jet& d, float cdt,
                                     const Jet& p, float cw) {
  Jet r;
  r.v  = base.v  + d.v  * cdt + p.v  * cw;
  r.w  = base.w  + d.w  * cdt + p.w  * cw;
  r.y  = base.y  + d.y  * cdt + p.y  * cw;
  r.ww = base.ww + d.ww * cdt + p.ww * cw;
  r.wy = base.wy + d.wy * cdt + p.wy * cw;
  return r;
}

__device__ __forceinline__ Jet ydec(const Jet& Y, float dt, float add) {
  Jet r;
  r.v  = Y.v  - F_KY * Y.v  * dt + add;
  r.w  = Y.w  - F_KY * Y.w  * dt;
  r.y  = Y.y  - F_KY * Y.y  * dt;
  r.ww = Y.ww - F_KY * Y.ww * dt;
  r.wy = Y.wy - F_KY * Y.wy * dt;
  return r;
}

__device__ __forceinline__ Jet driftvar(const Jet& pY, const Jet& pp) {
  Jet r;
  r.v  = F_R + F_SA * pY.v  - 0.5f * F_S2 * pp.v;
  r.w  =       F_SA * pY.w  - 0.5f * F_S2 * pp.w;
  r.y  =       F_SA * pY.y  - 0.5f * F_S2 * pp.y;
  r.ww =       F_SA * pY.ww - 0.5f * F_S2 * pp.ww;
  r.wy =       F_SA * pY.wy - 0.5f * F_S2 * pp.wy;
  return r;
}

} // namespace

// WAVE-AUTONOMOUS (R8 structure, unchanged): each wave owns 2 paths, full layer-2
// GEMM C[128][16] with W2 bf16 A-fragments in registers; B/C wave-private LDS;
// zero __syncthreads.
__global__ __launch_bounds__(256, 2) void ppgdpo_sim_kernel(
    const float* __restrict__ Wp, const float* __restrict__ Yp,
    const float* __restrict__ w1, const float* __restrict__ b1,
    const float* __restrict__ w2, const float* __restrict__ b2,
    const float* __restrict__ w3, const float* __restrict__ b3,
    const float* __restrict__ noise, float* __restrict__ ws) {
  __shared__ __align__(16) unsigned short Bsh[4][16 * STR];   // 17,408 B
  __shared__ __align__(16) float Csh[4][16 * JSTRC];          // 33,792 B

  const int t    = threadIdx.x;
  const int wv   = t >> 6;           // wave id (0..3)
  const int ln   = t & 63;           // lane in wave
  const int lp   = ln & 31;          // lane in path
  const int ph   = ln >> 5;          // path in wave (0/1)
  const int pblk = wv * 2 + ph;      // path in block
  const int b    = blockIdx.x * PPB + pblk;
  const int i    = b & (NPTS - 1);

  const int bx = ln & 15;            // MFMA col / A-row in tile
  const int kg = ln >> 4;            // MFMA k-group (0..3)

  // ---- W2 -> A fragments for ALL 8 row tiles (bf16, registers, once) ----
  bf16x8 A[8][4];
#pragma unroll
  for (int rt = 0; rt < 8; ++rt) {
#pragma unroll
    for (int kt = 0; kt < 4; ++kt) {
#pragma unroll
      for (int q = 0; q < 8; ++q)
        A[rt][kt][q] = (short)f2bf(w2[(kt * 32 + kg * 8 + q) * HID + rt * 16 + bx]);
    }
  }

  // per-lane layer-1/3 weights for owned units j0..j0+3 of this lane's path
  const int j0 = lp * 4;
  float w10[4], w11[4], w12[4], b1a[4], b2a[4], w3a[4];
  {
    float4 v;
    v = *(const float4*)(w1 + 0 * HID + j0); w10[0]=v.x; w10[1]=v.y; w10[2]=v.z; w10[3]=v.w;
    v = *(const float4*)(w1 + 1 * HID + j0); w11[0]=v.x; w11[1]=v.y; w11[2]=v.z; w11[3]=v.w;
    v = *(const float4*)(w1 + 2 * HID + j0); w12[0]=v.x; w12[1]=v.y; w12[2]=v.z; w12[3]=v.w;
    v = *(const float4*)(b1 + j0);           b1a[0]=v.x; b1a[1]=v.y; b1a[2]=v.z; b1a[3]=v.w;
    v = *(const float4*)(b2 + j0);           b2a[0]=v.x; b2a[1]=v.y; b2a[2]=v.z; b2a[3]=v.w;
    v = *(const float4*)(w3 + j0);           w3a[0]=v.x; w3a[1]=v.y; w3a[2]=v.z; w3a[3]=v.w;
  }
  const float b3r = b3[0];

  unsigned short* const myB = Bsh[wv];   // wave-private
  float* const myC = Csh[wv];            // wave-private
  const int cb = ph * 5;                 // this path's col base (0 or 5)

  auto mlp = [&](const Jet& Win, float tsub, const Jet& Yin) -> Jet {
    // ---- layer 1: 4 owned units -> cvt_pk bf16 pack -> b64 write per comp ----
    Jet h[4];
#pragma unroll
    for (int u = 0; u < 4; ++u) {
      Jet a;
      a.v  = fmaf(w10[u], Win.v, fmaf(w11[u], tsub, fmaf(w12[u], Yin.v, b1a[u])));
      a.w  = fmaf(w10[u], Win.w,  w12[u] * Yin.w);
      a.y  = fmaf(w10[u], Win.y,  w12[u] * Yin.y);
      a.ww = fmaf(w10[u], Win.ww, w12[u] * Yin.ww);
      a.wy = fmaf(w10[u], Win.wy, w12[u] * Yin.wy);
      h[u] = jtanh(a);
    }
    {
      float c0[4] = {h[0].v,  h[1].v,  h[2].v,  h[3].v};
      float c1[4] = {h[0].w,  h[1].w,  h[2].w,  h[3].w};
      float c2[4] = {h[0].y,  h[1].y,  h[2].y,  h[3].y};
      float c3[4] = {h[0].ww, h[1].ww, h[2].ww, h[3].ww};
      float c4[4] = {h[0].wy, h[1].wy, h[2].wy, h[3].wy};
      const float* cc[5] = {c0, c1, c2, c3, c4};
#pragma unroll
      for (int c = 0; c < 5; ++c) {
        uint2 wj;
        wj.x = pack2(cc[c][0], cc[c][1]);   // lanes j0, j0+1
        wj.y = pack2(cc[c][2], cc[c][3]);   // lanes j0+2, j0+3
        *reinterpret_cast<uint2*>(&myB[(cb + c) * STR + j0]) = wj;
      }
    }
    // (no barrier: same-wave DS ops are in-order)
    // ---- MFMA: 8 row tiles x 4 k tiles, single bf16 W2 ----
    bf16x8 bb[4];
#pragma unroll
    for (int kt = 0; kt < 4; ++kt)
      bb[kt] = *reinterpret_cast<const bf16x8*>(&myB[bx * STR + kt * 32 + kg * 8]);
#pragma unroll
    for (int rt = 0; rt < 8; ++rt) {
      f32x4 a_ = {0.f, 0.f, 0.f, 0.f};
#pragma unroll
      for (int kt = 0; kt < 4; ++kt)
        a_ = __builtin_amdgcn_mfma_f32_16x16x32_bf16(A[rt][kt], bb[kt], a_, 0, 0, 0);
      *reinterpret_cast<f32x4*>(&myC[bx * JSTRC + rt * 16 + kg * 4]) = a_;
    }
    // (no barrier)
    // ---- gather a2 (f32 float4) + tanh + layer 3 + per-path reduction ----
    float4 av[5];
#pragma unroll
    for (int c = 0; c < 5; ++c)
      av[c] = *reinterpret_cast<const float4*>(&myC[(cb + c) * JSTRC + j0]);
    float s[5] = {0.f, 0.f, 0.f, 0.f, 0.f};
#pragma unroll
    for (int u = 0; u < 4; ++u) {
      Jet a2;
      a2.v  = (u == 0 ? av[0].x : u == 1 ? av[0].y : u == 2 ? av[0].z : av[0].w) + b2a[u];
      a2.w  = (u == 0 ? av[1].x : u == 1 ? av[1].y : u == 2 ? av[1].z : av[1].w);
      a2.y  = (u == 0 ? av[2].x : u == 1 ? av[2].y : u == 2 ? av[2].z : av[2].w);
      a2.ww = (u == 0 ? av[3].x : u == 1 ? av[3].y : u == 2 ? av[3].z : av[3].w);
      a2.wy = (u == 0 ? av[4].x : u == 1 ? av[4].y : u == 2 ? av[4].z : av[4].w);
      Jet hh = jtanh(a2);
      s[0] = fmaf(hh.v,  w3a[u], s[0]);
      s[1] = fmaf(hh.w,  w3a[u], s[1]);
      s[2] = fmaf(hh.y,  w3a[u], s[2]);
      s[3] = fmaf(hh.ww, w3a[u], s[3]);
      s[4] = fmaf(hh.wy, w3a[u], s[4]);
    }
#pragma unroll
    for (int c = 0; c < 5; ++c) s[c] = path_allsum(s[c]);
    Jet pi;
    pi.v = s[0] + b3r; pi.w = s[1]; pi.y = s[2]; pi.ww = s[3]; pi.wy = s[4];
    return pi;
  };

  // ---- initial state jets (lanes of a path in lockstep) ----
  const float W0 = Wp[i];
  Jet L;
  L.v = __logf(fmaxf(W0, F_LBW));
  L.w = 1.0f / W0;
  L.y = 0.0f;
  L.ww = -1.0f / (W0 * W0);
  L.wy = 0.0f;
  Jet Yj;
  Yj.v = Yp[i]; Yj.w = 0.0f; Yj.y = 1.0f; Yj.ww = 0.0f; Yj.wy = 0.0f;
  float tmt = F_T;

  for (int m = 0; m < MSTEPS; ++m) {
    const float* nz = noise + (size_t)(m * 4) * BTOT + b;
    float z1b = nz[0];
    float z2b = nz[BTOT];
    float z1n = nz[2 * BTOT];
    float z2n = nz[3 * BTOT];
    float zWb = z1b, zYb = F_RHO * z1b + F_A * z2b;
    float zWn = z1n, zYn = F_RHO * z1n + F_A * z2n;
    float zWh1 = (zWb + zWn) * F_IS2, zYh1 = (zYb + zYn) * F_IS2;
    float zWh2 = (zWb - zWn) * F_IS2, zYh2 = (zYb - zYn) * F_IS2;

    Jet Win  = jexp(L);
    Jet pi_t = mlp(Win, tmt, Yj);

    Jet pY = jmul(pi_t, Yj);
    Jet pp = jmul(pi_t, pi_t);
    Jet dv = driftvar(pY, pp);

    float cWc  = F_SIG * (F_SDT * zWb);
    Jet lWc = jstep(L, dv, F_DT, pi_t, cWc);                      // coarse
    Jet Yc  = ydec(Yj, F_DT, F_SIGY * (F_SDT * zYb));

    float cWh1 = F_SIG * (F_SHALF * zWh1);
    Jet lWh = jstep(L, dv, F_HALF, pi_t, cWh1);                   // half 1
    Jet Yh  = ydec(Yj, F_HALF, F_SIGY * (F_SHALF * zYh1));

    Jet pih = mlp(jexp(lWh), tmt - F_HALF, Yh);                   // half 2
    Jet pYh = jmul(pih, Yh);
    Jet pph = jmul(pih, pih);
    Jet dvh = driftvar(pYh, pph);
    float cWh2 = F_SIG * (F_SHALF * zWh2);
    Jet lWf = jstep(lWh, dvh, F_HALF, pih, cWh2);
    Jet Yf  = ydec(Yh, F_HALF, F_SIGY * (F_SHALF * zYh2));

    // Richardson combination
    Jet raw, Yn;
    raw.v  = 2.0f * lWf.v  - lWc.v;
    raw.w  = 2.0f * lWf.w  - lWc.w;
    raw.y  = 2.0f * lWf.y  - lWc.y;
    raw.ww = 2.0f * lWf.ww - lWc.ww;
    raw.wy = 2.0f * lWf.wy - lWc.wy;
    Yn.v  = 2.0f * Yf.v  - Yc.v;
    Yn.w  = 2.0f * Yf.w  - Yc.w;
    Yn.y  = 2.0f * Yf.y  - Yc.y;
    Yn.ww = 2.0f * Yf.ww - Yc.ww;
    Yn.wy = 2.0f * Yf.wy - Yc.wy;

    // wealth floor: below log(LB_W) clamp value, zero derivatives
    bool ok = raw.v > F_LOGLBW;
    L.v  = ok ? raw.v  : F_LOGLBW;
    L.w  = ok ? raw.w  : 0.0f;
    L.y  = ok ? raw.y  : 0.0f;
    L.ww = ok ? raw.ww : 0.0f;
    L.wy = ok ? raw.wy : 0.0f;
    Yj = Yn;
    tmt -= F_DT;
  }

  // U = -0.25*exp(-4L); per-path dU/dW0, d2U/dW0^2, d2U/dW0dY0
  if (lp == 0) {
    float g = __expf(-4.0f * L.v);
    ws[b]            = g * L.w;
    ws[BTOT + b]     = g * (L.ww - 4.0f * L.w * L.w);
    ws[2 * BTOT + b] = g * (L.wy - 4.0f * L.w * L.y);
  }
}

__global__ void ppgdpo_reduce_kernel(const float* __restrict__ ws,
                                     const float* __restrict__ Wp,
                                     const float* __restrict__ Yp,
                                     float* __restrict__ out) {
  int i = threadIdx.x;  // 128 threads
  float sU = 0.f, sWW = 0.f, sWY = 0.f;
  for (int r = 0; r < RPTS; ++r) {
    int b = r * NPTS + i;
    sU  += ws[b];
    sWW += ws[BTOT + b];
    sWY += ws[2 * BTOT + b];
  }
  float lam = sU  * (1.0f / 32768.0f);
  float dW  = sWW * (1.0f / 1048576.0f);
  float dY  = sWY * (1.0f / 1048576.0f);

  float mu    = F_SIG * (0.8f * Yp[i]);
  float coeff = -1.0f / (Wp[i] * dW + 1e-8f);
  float myo   = coeff * (lam * (mu / F_S2));
  float hedge = coeff * ((float)(0.2 * 0.3 * 0.3) * dY / F_S2);
  float pi = myo + hedge;
  pi = fminf(fmaxf(pi, -2.0f), 2.0f);
  out[i] = pi;
}

extern "C" void kernel_launch(void* const* d_in, const int* in_sizes, int n_in,
                              void* d_out, int out_size, void* d_ws, size_t ws_size,
                              hipStream_t stream) {
  const float* W     = (const float*)d_in[0];
  const float* Y     = (const float*)d_in[2];
  const float* w1    = (const float*)d_in[3];
  const float* b1    = (const float*)d_in[4];
  const float* w2    = (const float*)d_in[5];
  const float* b2    = (const float*)d_in[6];
  const float* w3    = (const float*)d_in[7];
  const float* b3    = (const float*)d_in[8];
  const float* noise = (const float*)d_in[9];
  float* ws = (float*)d_ws;
  float* out = (float*)d_out;

  ppgdpo_sim_kernel<<<dim3(NBLK), dim3(256), 0, stream>>>(
      W, Y, w1, b1, w2, b2, w3, b3, noise, ws);
  ppgdpo_reduce_kernel<<<dim3(1), dim3(128), 0, stream>>>(ws, W, Y, out);
}